// Round 6
// baseline (10049.138 us; speedup 1.0000x reference)
//
#include <hip/hip_runtime.h>
#include <stdint.h>

typedef unsigned long long u64;

#define VOCAB 128
#define RD 128
#define DM 1024
#define NFF 6
#define BATCH 64
#define TSTEPS 512

// ---------------------------------------------------------------------------
// ws layout:
//   [0, 786432)          ffbT   [L][j][w] u64   (L<6, j<1024, w<16) thread-major
//   [786432, +2048)      ebits  [v][2]    u64   (v<128)
//   [788480, +2048)      headb  [v][2]    u64   (v<128)
//   [790528, +512)       losses [64]      double
// ---------------------------------------------------------------------------

// lgkm-only barrier: LDS writes drained, global (vmcnt) prefetch stays in
// flight across the barrier. The "memory" clobber also pins each layer's
// weight loads in place (blocks LICM from hoisting all 6 layers' loads).
#define BARRIER()                                            \
    do {                                                     \
        asm volatile("s_waitcnt lgkmcnt(0)" ::: "memory");   \
        __builtin_amdgcn_s_barrier();                        \
    } while (0)

// Pack ff sign bits, thread-major: word (L,w) for column j at ffbT[((L<<10)+j)*16+w].
// bit b of word = (ff[L][w*64+b][j] < 0)  (1 => -1)
__global__ void pack_ff(const float* __restrict__ ff, u64* __restrict__ ffbT) {
    int wid  = blockIdx.x * (blockDim.x >> 6) + (threadIdx.x >> 6); // 0..1535
    int lane = threadIdx.x & 63;
    int jt = wid & 15;
    int w  = (wid >> 4) & 15;
    int i  = wid >> 8;
    int j  = jt * 64 + lane;
    const float* src = ff + ((size_t)(i * DM) + w * 64) * DM + j;
    u64 word = 0;
#pragma unroll
    for (int b = 0; b < 64; ++b) {
        float v = src[(size_t)b * DM];
        word |= (u64)(v < 0.0f) << b;
    }
    ffbT[((size_t)((i << 10) + j)) * 16 + w] = word;
}

// Pack embed rows and head columns (tiny).
__global__ void pack_small(const float* __restrict__ emb, const float* __restrict__ head,
                           u64* __restrict__ eb, u64* __restrict__ hb) {
    int tid = threadIdx.x; // 0..255
    if (tid < 128) {
        int v = tid;
        for (int wd = 0; wd < 2; ++wd) {
            u64 word = 0;
            for (int l = 0; l < 64; ++l)
                word |= (u64)(emb[v * RD + wd * 64 + l] < 0.0f) << l;
            eb[v * 2 + wd] = word;
        }
    } else {
        int v = tid - 128;
        for (int wd = 0; wd < 2; ++wd) {
            u64 word = 0;
            for (int l = 0; l < 64; ++l)
                word |= (u64)(head[(wd * 64 + l) * VOCAB + v] < 0.0f) << l;
            hb[v * 2 + wd] = word;
        }
    }
}

// Main recurrent kernel: one block per batch row, thread j owns column j.
// Weights are STREAMED from L2 with one-layer-ahead register prefetch:
// per layer, issue 8 contiguous dwordx4 loads for layer i+1, then compute
// layer i from c[16]. Barriers are lgkm-only so the prefetch crosses them.
__global__ void __launch_bounds__(1024, 4)
brnn_main(const int* __restrict__ tokens,
          const float* __restrict__ initial_lat,
          const float* __restrict__ thr_lat,
          const u64* __restrict__ ffbT,
          const u64* __restrict__ eb,
          const u64* __restrict__ hb,
          double* __restrict__ losses) {
    const int b    = blockIdx.x;
    const int tid  = threadIdx.x;
    const int lane = tid & 63;
    const int wv   = tid >> 6;

    __shared__ __align__(16) u64 hbuf[2][16];
    __shared__ u64 hbL[2 * VOCAB]; // head bits, LDS-resident

    if (tid < 2 * VOCAB) hbL[tid] = hb[tid];

    // thresholds -> popcount cutoffs:  bit(-1) <=> pre < thr  <=>  acc >= cthr
    int cthr[NFF];
#pragma unroll
    for (int i = 0; i < NFF; ++i) {
        int thr = (int)rintf(thr_lat[i * DM + tid]); // round-half-even == jnp.round
        cthr[i] = ((DM - thr) >> 1) + 1;
    }

    // preload layer-0 weights (this thread's 128 B slice, 8x dwordx4)
    u64 c[16];
    {
        const ulonglong2* wp = (const ulonglong2*)(ffbT + (size_t)tid * 16);
#pragma unroll
        for (int k = 0; k < 8; ++k) {
            ulonglong2 v = wp[k];
            c[2 * k] = v.x; c[2 * k + 1] = v.y;
        }
    }

    // --- init h = sign(initial_lat), into buffer 0 ---
    {
        u64 m = __ballot(initial_lat[tid] < 0.0f);
        if (lane == 0) hbuf[0][wv] = m;
    }
    BARRIER();

    const int* toks = tokens + b * TSTEPS;
    double lacc = 0.0;
    int tok = toks[0];

    for (int t = 0; t < TSTEPS; ++t) {
        // prefetch next step's token (uniform s_load, hidden under this step)
        int tok_next = toks[(t + 1 < TSTEPS) ? (t + 1) : (TSTEPS - 1)];

        // prefetch embed bits for the end-of-step splice
        u64 enew = 0;
        if (wv == 0 && lane < 2) enew = eb[tok * 2 + lane];

        int p = 0;
#pragma unroll
        for (int i = 0; i < NFF; ++i) {
            // ---- issue next layer's weight loads (batched, stay in flight) ----
            const int nl = (i + 1) % NFF;
            const ulonglong2* wp =
                (const ulonglong2*)(ffbT + ((size_t)(nl << 10) + tid) * 16);
            ulonglong2 n0 = wp[0], n1 = wp[1], n2 = wp[2], n3 = wp[3],
                       n4 = wp[4], n5 = wp[5], n6 = wp[6], n7 = wp[7];

            // ---- compute this layer from c[] and LDS h ----
            const ulonglong2* hp = (const ulonglong2*)hbuf[p];
            int acc = 0;
#pragma unroll
            for (int q = 0; q < 8; ++q) {
                ulonglong2 hv = hp[q]; // broadcast ds_read_b128 (conflict-free)
                acc += __popcll(hv.x ^ c[2 * q]) + __popcll(hv.y ^ c[2 * q + 1]);
            }
            u64 m = __ballot(acc >= cthr[i]);
            if (lane == 0) hbuf[p ^ 1][wv] = m;

            // rotate prefetched weights into c (SSA renames; waitcnt lands
            // before first real use in next layer's xor)
            c[0] = n0.x;  c[1] = n0.y;  c[2] = n1.x;  c[3] = n1.y;
            c[4] = n2.x;  c[5] = n2.y;  c[6] = n3.x;  c[7] = n3.y;
            c[8] = n4.x;  c[9] = n4.y;  c[10] = n5.x; c[11] = n5.y;
            c[12] = n6.x; c[13] = n6.y; c[14] = n7.x; c[15] = n7.y;

            BARRIER();
            p ^= 1;
        }
        // p == 0 here; h5 in hbuf[0]

        // --- head + log-softmax + loss + embed splice (wave 0 only) ---
        if (wv == 0) {
            u64 r0 = hbuf[0][14], r1 = hbuf[0][15];
            u64 h0a = hbL[lane * 2 + 0],        h0b = hbL[lane * 2 + 1];
            u64 h1a = hbL[(lane + 64) * 2 + 0], h1b = hbL[(lane + 64) * 2 + 1];
            int d0 = 128 - 2 * (__popcll(r0 ^ h0a) + __popcll(r1 ^ h0b));
            int d1 = 128 - 2 * (__popcll(r0 ^ h1a) + __popcll(r1 ^ h1b));
            float l0 = (float)d0 * (1.0f / 16.0f);
            float l1 = (float)d1 * (1.0f / 16.0f);
            float mx = fmaxf(l0, l1);
#pragma unroll
            for (int s = 32; s >= 1; s >>= 1) mx = fmaxf(mx, __shfl_xor(mx, s));
            float se = __expf(l0 - mx) + __expf(l1 - mx);
#pragma unroll
            for (int s = 32; s >= 1; s >>= 1) se += __shfl_xor(se, s);
            int   tl   = tok & 63;
            float la   = __shfl(l0, tl);
            float lb   = __shfl(l1, tl);
            float ltok = (tok >> 6) ? lb : la;
            lacc += (double)(mx + __logf(se) - ltok);
            // splice x_new read-part = sign(embed[tok]) into words 14,15
            if (lane < 2) hbuf[0][14 + lane] = enew;
        }
        BARRIER();
        tok = tok_next;
    }

    if (tid == 0) losses[b] = lacc;
}

__global__ void reduce_loss(const double* __restrict__ losses, float* __restrict__ out) {
    int lane = threadIdx.x; // 64 threads, 1 wave
    double v = losses[lane];
#pragma unroll
    for (int s = 32; s >= 1; s >>= 1) v += __shfl_down(v, s);
    if (lane == 0) out[0] = (float)(v * (1.0 / ((double)BATCH * (double)TSTEPS)));
}

extern "C" void kernel_launch(void* const* d_in, const int* in_sizes, int n_in,
                              void* d_out, int out_size, void* d_ws, size_t ws_size,
                              hipStream_t stream) {
    const int*   tokens  = (const int*)d_in[0];   // (64, 512) int32
    const float* initial = (const float*)d_in[1]; // (1024,)
    const float* embed   = (const float*)d_in[2]; // (128, 128)
    const float* ff      = (const float*)d_in[3]; // (6, 1024, 1024)
    const float* head    = (const float*)d_in[4]; // (128, 128)
    const float* thrl    = (const float*)d_in[5]; // (6, 1024)

    char* ws = (char*)d_ws;
    u64*    ffbT   = (u64*)ws;                      // 786432 B
    u64*    eb     = (u64*)(ws + 786432);           // 2048 B
    u64*    hb     = (u64*)(ws + 786432 + 2048);    // 2048 B
    double* losses = (double*)(ws + 786432 + 4096); // 512 B

    pack_ff<<<384, 256, 0, stream>>>(ff, ffbT);
    pack_small<<<1, 256, 0, stream>>>(embed, head, eb, hb);
    brnn_main<<<BATCH, 1024, 0, stream>>>(tokens, initial, thrl, ffbT, eb, hb, losses);
    reduce_loss<<<1, 64, 0, stream>>>(losses, (float*)d_out);
}